// Round 1
// baseline (375.066 us; speedup 1.0000x reference)
//
#include <hip/hip_runtime.h>

// KMeans assignment: costs[i] = min_k ||x_i-c_k||^2, indices[i] = argmin_k.
// argmin over k of (c2[k] - 2*dot(x,c_k)); x2 additive, added at the end.
// Cross term via split-f16 3-pass MFMA (xh.ch + xl.ch + xh.cl), err ~1e-6.
// R6: barrier-free main loop.
//  - Bh is no longer staged in LDS: both Bh and Bl fragments are register-
//    prefetched straight from L2 (B = 512 KB total, L2-resident per XCD).
//    Register deps make the compiler emit *counted* vmcnt waits -- the old
//    per-chunk __syncthreads forced vmcnt(0)+lgkmcnt(0) drains (the
//    structural ~20% stall) and kept all 8 waves/CU in lockstep.
//  - Zero __syncthreads in the chunk loop; waves slip freely.
//  - A LDS layout XOR-swizzled (u16 off ^= (g&7)<<3): the staging writes
//    were 16-way bank-conflicted (same row, k-groups 2048B apart -> banks
//    0-3); swizzle spreads them over all 32 banks. Fragment reads stay
//    conflict-free (per-read the XOR is a constant row permutation).
//  - s_setprio(1) around the MFMA cluster (waves now phase-diverse -> T5
//    regime; was null under lockstep).
// LDS = 64KB (A) + 2KB reduce -> still 2 blocks/CU.
// N=131072, D=128, K=1024.  d_out = [costs (N f32), indices-as-f32 (N)].

typedef _Float16 f16x8 __attribute__((ext_vector_type(8)));
typedef float    f32x4 __attribute__((ext_vector_type(4)));
typedef unsigned short u16;

constexpr int N = 131072, D = 128, K = 1024;
constexpr int MT = 128;   // points per block

union H2U { _Float16 h; unsigned short u; };

// ---- prep: centers -> hi/lo f16 in fragment-major tiled layout + exact c2 ----
// ushort idx: (((cb*4 + kc)*4 + q)*128 + c%128)*8 + j, k = kc*32 + q*8 + j
__global__ void prep_centers(const float* __restrict__ centers,
                             u16* __restrict__ Bh, u16* __restrict__ Bl,
                             float* __restrict__ c2) {
  const int wave = threadIdx.x >> 6, lane = threadIdx.x & 63;
  const int c = blockIdx.x * 4 + wave;          // one wave per center
  const float2 v = ((const float2*)(centers + (size_t)c * D))[lane];
  float s = v.x * v.x + v.y * v.y;
  #pragma unroll
  for (int off = 32; off; off >>= 1) s += __shfl_xor(s, off, 64);
  if (lane == 0) c2[c] = s;

  H2U h0, h1, l0, l1;
  h0.h = (_Float16)v.x;  l0.h = (_Float16)(v.x - (float)h0.h);
  h1.h = (_Float16)v.y;  l1.h = (_Float16)(v.y - (float)h1.h);
  const int cb = c >> 7, cm = c & 127;
  const int kc = lane >> 4, q = (lane >> 2) & 3, j0 = (lane & 3) * 2;
  const size_t off = (((size_t)(cb * 4 + kc) * 4 + q) * 128 + cm) * 8 + j0;
  *(unsigned*)(Bh + off) = (unsigned)h0.u | ((unsigned)h1.u << 16);
  *(unsigned*)(Bl + off) = (unsigned)l0.u | ((unsigned)l1.u << 16);
}

// ---- main: 128 pts x 1024 centers per block; wave tile 64x64 (2x2 waves) ----
__global__ __launch_bounds__(256, 2) void kmeans_mfma(
    const float* __restrict__ x,
    const u16* __restrict__ Bh_g, const u16* __restrict__ Bl_g,
    const float* __restrict__ c2g,
    float* __restrict__ out_cost, float* __restrict__ out_idx)
{
  // 66 KB: A [0,32768) u16 (swizzled), reduce arrays [32768,33792)
  __shared__ __align__(16) u16 smem[33792];
  u16* Ah = smem;            // [g16][m128][j8] swizzled   32 KB
  u16* Al = smem + 16384;    //                            32 KB

  const int tid = threadIdx.x;
  const int wave = tid >> 6, lane = tid & 63;
  const int wr = wave >> 1, wc = wave & 1;    // wave row/col in 2x2
  const int q = lane >> 4, ln = lane & 15;
  const int m0 = blockIdx.x * MT;

  // ---- stage A tile: fp32 -> (hi,lo) f16, XOR-swizzled tiled layout ----
  #pragma unroll
  for (int i = 0; i < 16; ++i) {
    const int flat = i * 256 + tid;            // 4096 float4s = 128x128 floats
    const int m = flat >> 5, c4 = flat & 31, k0 = c4 * 4;
    const float4 v = *(const float4*)(x + (size_t)(m0 + m) * D + k0);
    const int g = k0 >> 3;                     // k-group = kc*4+qq, [0,16)
    const int j0 = k0 & 7;                     // 0 or 4
    const float vv[4] = {v.x, v.y, v.z, v.w};
    H2U h[4], l[4];
    #pragma unroll
    for (int z = 0; z < 4; ++z) {
      h[z].h = (_Float16)vv[z];
      l[z].h = (_Float16)(vv[z] - (float)h[z].h);
    }
    const int off = ((g * 128 + m) * 8 + j0) ^ ((g & 7) << 3);
    uint2 hp, lp;
    hp.x = h[0].u | ((unsigned)h[1].u << 16); hp.y = h[2].u | ((unsigned)h[3].u << 16);
    lp.x = l[0].u | ((unsigned)l[1].u << 16); lp.y = l[2].u | ((unsigned)l[3].u << 16);
    *(uint2*)(Ah + off) = hp;
    *(uint2*)(Al + off) = lp;
  }
  __syncthreads();   // the ONLY barrier before the final reduce

  // ---- x2 per point (thread tid<128 owns m=tid); A persists in LDS ----
  float x2m = 0.f;
  if (tid < MT) {
    #pragma unroll
    for (int g = 0; g < 16; ++g) {
      const int off = ((g * 128 + tid) * 8) ^ ((g & 7) << 3);
      const f16x8 hv = *(const f16x8*)(Ah + off);
      const f16x8 lv = *(const f16x8*)(Al + off);
      #pragma unroll
      for (int e = 0; e < 8; ++e) {
        const float xv = (float)hv[e] + (float)lv[e];
        x2m += xv * xv;
      }
    }
  }

  // B register fragment addresses (L2-resident, fragment-major)
  auto bhPtr = [&](int cc, int t) {
    return (const f16x8*)(Bh_g +
        ((size_t)(cc * 4 + q) * 128 + wc * 64 + t * 16 + ln) * 8);
  };
  auto blPtr = [&](int cc, int t) {
    return (const f16x8*)(Bl_g +
        ((size_t)(cc * 4 + q) * 128 + wc * 64 + t * 16 + ln) * 8);
  };

  float bestV[16]; int bestI[16];
  #pragma unroll
  for (int b = 0; b < 16; ++b) { bestV[b] = 3.4e38f; bestI[b] = 0; }

  f16x8 bhc[4], blc[4], bhn[4], bln[4];
  #pragma unroll
  for (int t = 0; t < 4; ++t) { bhc[t] = *bhPtr(0, t); blc[t] = *blPtr(0, t); }

  for (int ct = 0; ct < 8; ++ct) {
    f32x4 acc[4][4];
    #pragma unroll
    for (int mt = 0; mt < 4; ++mt)
      #pragma unroll
      for (int nt = 0; nt < 4; ++nt)
        acc[mt][nt] = (f32x4){0.f, 0.f, 0.f, 0.f};

    // c2 for this ct tile, direct from L2; hidden under the 4-chunk compute
    float c2v[4];
    #pragma unroll
    for (int nt = 0; nt < 4; ++nt)
      c2v[nt] = c2g[ct * 128 + wc * 64 + nt * 16 + ln];

    #pragma unroll
    for (int kc = 0; kc < 4; ++kc) {
      const int cc = ct * 4 + kc;              // chunk id
      if (cc < 31) {                           // prefetch next chunk -> regs
        #pragma unroll
        for (int t = 0; t < 4; ++t) {
          bhn[t] = *bhPtr(cc + 1, t);
          bln[t] = *blPtr(cc + 1, t);
        }
      }

      f16x8 ah[4], al[4];
      #pragma unroll
      for (int t = 0; t < 4; ++t) {
        const int gg = kc * 4 + q;
        const int moff = ((gg * 128 + wr * 64 + t * 16 + ln) * 8) ^ ((gg & 7) << 3);
        ah[t] = *(const f16x8*)(Ah + moff);
        al[t] = *(const f16x8*)(Al + moff);
      }

      // 3-pass split-f16: 48 MFMA per chunk (counted vmcnt waits on bhc/blc
      // are inserted by the compiler from register deps -- no barrier)
      __builtin_amdgcn_s_setprio(1);
      #pragma unroll
      for (int mt = 0; mt < 4; ++mt)
        #pragma unroll
        for (int nt = 0; nt < 4; ++nt)
          acc[mt][nt] = __builtin_amdgcn_mfma_f32_16x16x32_f16(ah[mt], bhc[nt], acc[mt][nt], 0, 0, 0);
      #pragma unroll
      for (int mt = 0; mt < 4; ++mt)
        #pragma unroll
        for (int nt = 0; nt < 4; ++nt)
          acc[mt][nt] = __builtin_amdgcn_mfma_f32_16x16x32_f16(al[mt], bhc[nt], acc[mt][nt], 0, 0, 0);
      #pragma unroll
      for (int mt = 0; mt < 4; ++mt)
        #pragma unroll
        for (int nt = 0; nt < 4; ++nt)
          acc[mt][nt] = __builtin_amdgcn_mfma_f32_16x16x32_f16(ah[mt], blc[nt], acc[mt][nt], 0, 0, 0);
      __builtin_amdgcn_s_setprio(0);

      #pragma unroll
      for (int t = 0; t < 4; ++t) { bhc[t] = bhn[t]; blc[t] = bln[t]; }
    }

    // epilogue: s = c2 - 2*dot; running min (n strictly increasing per lane)
    #pragma unroll
    for (int nt = 0; nt < 4; ++nt) {
      const int n = ct * 128 + wc * 64 + nt * 16 + ln;
      #pragma unroll
      for (int mt = 0; mt < 4; ++mt)
        #pragma unroll
        for (int r = 0; r < 4; ++r) {
          const float s = __builtin_fmaf(-2.f, acc[mt][nt][r], c2v[nt]);
          const int b = mt * 4 + r;
          if (s < bestV[b]) { bestV[b] = s; bestI[b] = n; }
        }
    }
  }

  // ---- reduce across the 16 lanes (ln) sharing the same m rows ----
  #pragma unroll
  for (int b = 0; b < 16; ++b) {
    float v = bestV[b]; int idx = bestI[b];
    #pragma unroll
    for (int off = 1; off < 16; off <<= 1) {
      const float ov = __shfl_xor(v, off, 64);
      const int   oi = __shfl_xor(idx, off, 64);
      if (ov < v || (ov == v && oi < idx)) { v = ov; idx = oi; }
    }
    bestV[b] = v; bestI[b] = idx;
  }

  float* redV = (float*)(smem + 32768);  // 1 KB (256 floats)
  int*   redI = (int*)(smem + 33280);    // 1 KB (256 ints)
  if (ln == 0) {
    #pragma unroll
    for (int b = 0; b < 16; ++b) {
      const int ml = wr * 64 + (b >> 2) * 16 + q * 4 + (b & 3);
      redV[ml * 2 + wc] = bestV[b];
      redI[ml * 2 + wc] = bestI[b];
    }
  }
  __syncthreads();
  if (tid < MT) {
    float v = redV[tid * 2]; int idx = redI[tid * 2];
    const float v1 = redV[tid * 2 + 1]; const int i1 = redI[tid * 2 + 1];
    if (v1 < v || (v1 == v && i1 < idx)) { v = v1; idx = i1; }
    float cost = x2m + v;
    if (cost < 0.f) cost = 0.f;          // clamp like reference
    out_cost[m0 + tid] = cost;
    out_idx[m0 + tid]  = (float)idx;
  }
}

extern "C" void kernel_launch(void* const* d_in, const int* in_sizes, int n_in,
                              void* d_out, int out_size, void* d_ws, size_t ws_size,
                              hipStream_t stream) {
  const float* x       = (const float*)d_in[0];
  const float* centers = (const float*)d_in[1];
  u16*   Bh = (u16*)d_ws;                    // 256 KB
  u16*   Bl = Bh + (size_t)K * D;            // 256 KB
  float* c2 = (float*)(Bl + (size_t)K * D);  // 4 KB
  float* out_cost = (float*)d_out;
  float* out_idx  = out_cost + N;

  prep_centers<<<K / 4, 256, 0, stream>>>(centers, Bh, Bl, c2);
  kmeans_mfma<<<N / MT, 256, 0, stream>>>(x, Bh, Bl, c2, out_cost, out_idx);
}

// Round 3
// 176.881 us; speedup vs baseline: 2.1204x; 2.1204x over previous
//
#include <hip/hip_runtime.h>

// KMeans assignment: costs[i] = min_k ||x_i-c_k||^2, indices[i] = argmin_k.
// argmin over k of (c2[k] - 2*dot(x,c_k)); x2 additive, added at the end.
// Cross term via split-f16 3-pass MFMA (xh.ch + xl.ch + xh.cl), err ~1e-6.
// R8 = R5 structure + two proven/safe changes, exact R5 epilogue:
//  - A LDS layout XOR-swizzled (u16 off ^= (g&7)<<3): R6 proved this kills
//    the A-staging-write bank conflicts (3.68M -> 8.2K cycles).
//  - Pass 3 (ah x blc, register/LDS-A only, no Bh-barrier dependency)
//    hoisted BEFORE the per-chunk barrier: post-barrier LDS burst shrinks
//    12 -> 4 reads/wave, barrier-straggler window fills with MFMAs.
//  - s_setprio(1) around MFMA clusters.
// REVERTED (R7 fail): packed-key argmin. Truncating 5 mantissa bits gave
// 0.004 compare granularity -> near-tie argmin flips -> index absmax 758.
// Argmin needs full-precision f32 compare + separate index select.
// Known-bad (R6): all-register B double-buffer -> spills -> 365MB scratch.
// LDS = 64KB (A) + 16KB (Bh dbuf) = 80KB -> 2 blocks/CU.
// N=131072, D=128, K=1024.  d_out = [costs (N f32), indices-as-f32 (N)].

typedef _Float16 f16x8 __attribute__((ext_vector_type(8)));
typedef float    f32x4 __attribute__((ext_vector_type(4)));
typedef unsigned short u16;

constexpr int N = 131072, D = 128, K = 1024;
constexpr int MT = 128;   // points per block

union H2U { _Float16 h; unsigned short u; };

__device__ inline void gl_lds16(const void* g, void* l) {
  __builtin_amdgcn_global_load_lds(
      (const __attribute__((address_space(1))) unsigned int*)g,
      (__attribute__((address_space(3))) unsigned int*)l, 16, 0, 0);
}

// ---- prep: centers -> hi/lo f16 in fragment-major tiled layout + exact c2 ----
// ushort idx: (((cb*4 + kc)*4 + q)*128 + c%128)*8 + j, k = kc*32 + q*8 + j
__global__ void prep_centers(const float* __restrict__ centers,
                             u16* __restrict__ Bh, u16* __restrict__ Bl,
                             float* __restrict__ c2) {
  const int wave = threadIdx.x >> 6, lane = threadIdx.x & 63;
  const int c = blockIdx.x * 4 + wave;          // one wave per center
  const float2 v = ((const float2*)(centers + (size_t)c * D))[lane];
  float s = v.x * v.x + v.y * v.y;
  #pragma unroll
  for (int off = 32; off; off >>= 1) s += __shfl_xor(s, off, 64);
  if (lane == 0) c2[c] = s;

  H2U h0, h1, l0, l1;
  h0.h = (_Float16)v.x;  l0.h = (_Float16)(v.x - (float)h0.h);
  h1.h = (_Float16)v.y;  l1.h = (_Float16)(v.y - (float)h1.h);
  const int cb = c >> 7, cm = c & 127;
  const int kc = lane >> 4, q = (lane >> 2) & 3, j0 = (lane & 3) * 2;
  const size_t off = (((size_t)(cb * 4 + kc) * 4 + q) * 128 + cm) * 8 + j0;
  *(unsigned*)(Bh + off) = (unsigned)h0.u | ((unsigned)h1.u << 16);
  *(unsigned*)(Bl + off) = (unsigned)l0.u | ((unsigned)l1.u << 16);
}

// ---- main: 128 pts x 1024 centers per block; wave tile 64x64 (2x2 waves) ----
__global__ __launch_bounds__(256, 2) void kmeans_mfma(
    const float* __restrict__ x,
    const u16* __restrict__ Bh_g, const u16* __restrict__ Bl_g,
    const float* __restrict__ c2g,
    float* __restrict__ out_cost, float* __restrict__ out_idx)
{
  // 80 KB total: A [0,32768) u16 swizzled, Bh dbuf [32768,40960) (2 x 4096)
  __shared__ __align__(16) u16 smem[40960];
  u16* Ah = smem;            // [g16][m128][j8] swizzled  32 KB
  u16* Al = smem + 16384;    //                           32 KB

  const int tid = threadIdx.x;
  const int wave = tid >> 6, lane = tid & 63;
  const int wr = wave >> 1, wc = wave & 1;    // wave row/col in 2x2
  const int q = lane >> 4, ln = lane & 15;
  const int m0 = blockIdx.x * MT;

  // ---- stage A tile: fp32 -> (hi,lo) f16, XOR-swizzled tiled layout ----
  #pragma unroll
  for (int i = 0; i < 16; ++i) {
    const int flat = i * 256 + tid;            // 4096 float4s = 128x128 floats
    const int m = flat >> 5, c4 = flat & 31, k0 = c4 * 4;
    const float4 v = *(const float4*)(x + (size_t)(m0 + m) * D + k0);
    const int g = k0 >> 3;                     // k-group in [0,16)
    const int j0 = k0 & 7;                     // 0 or 4
    const float vv[4] = {v.x, v.y, v.z, v.w};
    H2U h[4], l[4];
    #pragma unroll
    for (int z = 0; z < 4; ++z) {
      h[z].h = (_Float16)vv[z];
      l[z].h = (_Float16)(vv[z] - (float)h[z].h);
    }
    const int off = ((g * 128 + m) * 8 + j0) ^ ((g & 7) << 3);
    uint2 hp, lp;
    hp.x = h[0].u | ((unsigned)h[1].u << 16); hp.y = h[2].u | ((unsigned)h[3].u << 16);
    lp.x = l[0].u | ((unsigned)l[1].u << 16); lp.y = l[2].u | ((unsigned)l[3].u << 16);
    *(uint2*)(Ah + off) = hp;
    *(uint2*)(Al + off) = lp;
  }
  __syncthreads();

  // ---- x2 per point (thread tid<128 owns m=tid); A persists in LDS ----
  float x2m = 0.f;
  if (tid < MT) {
    #pragma unroll
    for (int g = 0; g < 16; ++g) {
      const int off = ((g * 128 + tid) * 8) ^ ((g & 7) << 3);
      const f16x8 hv = *(const f16x8*)(Ah + off);
      const f16x8 lv = *(const f16x8*)(Al + off);
      #pragma unroll
      for (int e = 0; e < 8; ++e) {
        const float xv = (float)hv[e] + (float)lv[e];
        x2m += xv * xv;
      }
    }
  }

  // Bh double-buffer staging (8 KB per chunk), linear layout (gl_lds rule)
  auto stageBh = [&](int cc, int p) {
    const size_t gbase = (size_t)cc * 4096;   // u16 per chunk (128c x 32k)
    u16* buf = smem + 32768 + p * 4096;
    #pragma unroll
    for (int i = 0; i < 2; ++i) {
      const size_t eoff = (size_t)i * 2048 + (size_t)wave * 512;  // wave-uniform
      gl_lds16(Bh_g + gbase + eoff + (size_t)lane * 8, buf + eoff);
    }
  };
  // Bl register fragment address (L2-resident, fragment-major)
  auto blPtr = [&](int cc, int t) {
    return (const f16x8*)(Bl_g +
        ((size_t)(cc * 4 + q) * 128 + wc * 64 + t * 16 + ln) * 8);
  };

  float bestV[16]; int bestI[16];
  #pragma unroll
  for (int b = 0; b < 16; ++b) { bestV[b] = 3.4e38f; bestI[b] = 0; }

  stageBh(0, 0);
  f16x8 blc[4], bln[4];
  #pragma unroll
  for (int t = 0; t < 4; ++t) blc[t] = *blPtr(0, t);

  for (int ct = 0; ct < 8; ++ct) {
    f32x4 acc[4][4];
    #pragma unroll
    for (int mt = 0; mt < 4; ++mt)
      #pragma unroll
      for (int nt = 0; nt < 4; ++nt)
        acc[mt][nt] = (f32x4){0.f, 0.f, 0.f, 0.f};

    // c2 for this ct tile, direct from L2; hidden under the 4-chunk compute
    float c2v[4];
    #pragma unroll
    for (int nt = 0; nt < 4; ++nt)
      c2v[nt] = c2g[ct * 128 + wc * 64 + nt * 16 + ln];

    #pragma unroll
    for (int kc = 0; kc < 4; ++kc) {
      const int cc = ct * 4 + kc;              // chunk id, parity = cc&1

      // -- pre-barrier: A fragments + pass 3 (no Bh dependency) --
      f16x8 ah[4], al[4];
      #pragma unroll
      for (int t = 0; t < 4; ++t) {
        const int gg = kc * 4 + q;
        const int moff = ((gg * 128 + wr * 64 + t * 16 + ln) * 8) ^ ((gg & 7) << 3);
        ah[t] = *(const f16x8*)(Ah + moff);
        al[t] = *(const f16x8*)(Al + moff);
      }
      __builtin_amdgcn_s_setprio(1);
      #pragma unroll
      for (int mt = 0; mt < 4; ++mt)
        #pragma unroll
        for (int nt = 0; nt < 4; ++nt)
          acc[mt][nt] = __builtin_amdgcn_mfma_f32_16x16x32_f16(ah[mt], blc[nt], acc[mt][nt], 0, 0, 0);
      __builtin_amdgcn_s_setprio(0);

      __syncthreads();   // all waves' vmcnt drained -> buf[cc&1] staged

      if (cc < 31) {
        stageBh(cc + 1, (cc + 1) & 1);         // Bh prefetch, 1 chunk ahead
        #pragma unroll
        for (int t = 0; t < 4; ++t) bln[t] = *blPtr(cc + 1, t);  // Bl prefetch
      }
      const u16* buf = smem + 32768 + (cc & 1) * 4096;
      f16x8 bh[4];
      #pragma unroll
      for (int t = 0; t < 4; ++t)
        bh[t] = *(const f16x8*)(buf + (q * 128 + wc * 64 + t * 16 + ln) * 8);

      // -- post-barrier: passes 1+2 (32 MFMA) --
      __builtin_amdgcn_s_setprio(1);
      #pragma unroll
      for (int mt = 0; mt < 4; ++mt)
        #pragma unroll
        for (int nt = 0; nt < 4; ++nt)
          acc[mt][nt] = __builtin_amdgcn_mfma_f32_16x16x32_f16(ah[mt], bh[nt], acc[mt][nt], 0, 0, 0);
      #pragma unroll
      for (int mt = 0; mt < 4; ++mt)
        #pragma unroll
        for (int nt = 0; nt < 4; ++nt)
          acc[mt][nt] = __builtin_amdgcn_mfma_f32_16x16x32_f16(al[mt], bh[nt], acc[mt][nt], 0, 0, 0);
      __builtin_amdgcn_s_setprio(0);

      #pragma unroll
      for (int t = 0; t < 4; ++t) blc[t] = bln[t];
    }

    // epilogue: s = c2 - 2*dot; running min (n strictly increasing per lane)
    #pragma unroll
    for (int nt = 0; nt < 4; ++nt) {
      const int n = ct * 128 + wc * 64 + nt * 16 + ln;
      #pragma unroll
      for (int mt = 0; mt < 4; ++mt)
        #pragma unroll
        for (int r = 0; r < 4; ++r) {
          const float s = __builtin_fmaf(-2.f, acc[mt][nt][r], c2v[nt]);
          const int b = mt * 4 + r;
          if (s < bestV[b]) { bestV[b] = s; bestI[b] = n; }
        }
    }
  }

  // ---- reduce across the 16 lanes (ln) sharing the same m rows ----
  #pragma unroll
  for (int b = 0; b < 16; ++b) {
    float v = bestV[b]; int idx = bestI[b];
    #pragma unroll
    for (int off = 1; off < 16; off <<= 1) {
      const float ov = __shfl_xor(v, off, 64);
      const int   oi = __shfl_xor(idx, off, 64);
      if (ov < v || (ov == v && oi < idx)) { v = ov; idx = oi; }
    }
    bestV[b] = v; bestI[b] = idx;
  }

  __syncthreads();                       // all Bh-buf reads done -> overlay
  float* redV = (float*)(smem + 32768);  // 1 KB
  int*   redI = (int*)(smem + 33280);    // 1 KB
  if (ln == 0) {
    #pragma unroll
    for (int b = 0; b < 16; ++b) {
      const int ml = wr * 64 + (b >> 2) * 16 + q * 4 + (b & 3);
      redV[ml * 2 + wc] = bestV[b];
      redI[ml * 2 + wc] = bestI[b];
    }
  }
  __syncthreads();
  if (tid < MT) {
    float v = redV[tid * 2]; int idx = redI[tid * 2];
    const float v1 = redV[tid * 2 + 1]; const int i1 = redI[tid * 2 + 1];
    if (v1 < v || (v1 == v && i1 < idx)) { v = v1; idx = i1; }
    float cost = x2m + v;
    if (cost < 0.f) cost = 0.f;          // clamp like reference
    out_cost[m0 + tid] = cost;
    out_idx[m0 + tid]  = (float)idx;
  }
}

extern "C" void kernel_launch(void* const* d_in, const int* in_sizes, int n_in,
                              void* d_out, int out_size, void* d_ws, size_t ws_size,
                              hipStream_t stream) {
  const float* x       = (const float*)d_in[0];
  const float* centers = (const float*)d_in[1];
  u16*   Bh = (u16*)d_ws;                    // 256 KB
  u16*   Bl = Bh + (size_t)K * D;            // 256 KB
  float* c2 = (float*)(Bl + (size_t)K * D);  // 4 KB
  float* out_cost = (float*)d_out;
  float* out_idx  = out_cost + N;

  prep_centers<<<K / 4, 256, 0, stream>>>(centers, Bh, Bl, c2);
  kmeans_mfma<<<N / MT, 256, 0, stream>>>(x, Bh, Bl, c2, out_cost, out_idx);
}